// Round 1
// baseline (615.936 us; speedup 1.0000x reference)
//
#include <hip/hip_runtime.h>

// snn_layer: out[b,u,t] = (sum_f in[b,f,t] * w[f,u] > 1.0f) ? 1.0f : 0.0f
// B=128 F=512 T=256 U=1024, fp32 in/out.
//
// Strategy: fp32 has no MFMA on CDNA4 (old kernel: VALUBusy 66% = LDS-feed
// ceiling of the vector-FMA path). Move the GEMM to matrix cores via exact
// bf16 hi/lo split:  h ~= Ah*Bh + Ah*Bl + Al*Bh  (error ~2e-6, dominated by
// fp32 accumulation rounding). The output is a threshold at h==1.0, so any
// element within 1e-3 of the threshold is recomputed in fp32 with the SAME
// sequential fmaf order as the previously-verified fp32 kernel -> flip-free.
//
// Kernel 1 (prepass): transpose+split W[f][u] -> wT_{hi,lo}[u][f] bf16 and
//                     X[b][f][t] -> xT_{hi,lo}[b][t][f] bf16 (both operands
//                     must be k-contiguous for MFMA fragment loads).
// Kernel 2 (main):    m97-style 128x128 tile GEMM, BK=32, 4 waves, 16x16x32
//                     bf16 MFMA, global_load_lds width-16 staging, 3 passes
//                     per chunk (hi*hi, hi*lo, lo*hi).
// Fallback: if d_ws too small, launch the old verified fp32 kernel.

#define BB 128
#define FF 512
#define TT 256
#define UU 1024

typedef float v4f __attribute__((ext_vector_type(4)));
typedef short v8s __attribute__((ext_vector_type(8)));

__device__ __forceinline__ unsigned short bf16rn(float x) {
    unsigned u = __float_as_uint(x);
    u = u + 0x7FFFu + ((u >> 16) & 1u);   // round-to-nearest-even
    return (unsigned short)(u >> 16);
}
__device__ __forceinline__ float bf16tof(unsigned short h) {
    return __uint_as_float(((unsigned)h) << 16);
}

// ---------------------------------------------------------------------------
// Prepass: transpose + hi/lo split.
// Panels of 512(f) x 256(cols): z<128 -> X batch z (row stride TT);
// z in [128,132) -> W column-strip s=z-128 (row stride UU).
// Output row-major [col][f], f contiguous (512 bf16 = 1024 B rows).
// ---------------------------------------------------------------------------
__global__ __launch_bounds__(256)
void prepass_kernel(const float* __restrict__ in, const float* __restrict__ w,
                    unsigned short* __restrict__ xth, unsigned short* __restrict__ xtl,
                    unsigned short* __restrict__ wth, unsigned short* __restrict__ wtl) {
    __shared__ float Ls[64][65];   // +1 pad: conflict-free column reads

    const int z = blockIdx.z;
    const float* src;
    int srow;
    unsigned short *dh, *dl;
    if (z < BB) {
        src = in + (size_t)z * FF * TT;  srow = TT;
        dh = xth + (size_t)z * TT * FF;  dl = xtl + (size_t)z * TT * FF;
    } else {
        const int s = z - BB;
        src = w + s * 256;               srow = UU;
        dh = wth + (size_t)s * 256 * FF; dl = wtl + (size_t)s * 256 * FF;
    }
    const int f0 = blockIdx.y * 64;   // f-tile
    const int c0 = blockIdx.x * 64;   // col-tile (t or u-local)
    const int tid = threadIdx.x;
    const int r  = tid >> 4;          // 0..15
    const int c4 = (tid & 15) * 4;    // 0..60

    // load 64x64 fp32 tile (coalesced float4 along cols)
#pragma unroll
    for (int i = 0; i < 4; i++) {
        const float4 v = *(const float4*)&src[(size_t)(f0 + r + 16 * i) * srow + c0 + c4];
        Ls[r + 16 * i][c4 + 0] = v.x;
        Ls[r + 16 * i][c4 + 1] = v.y;
        Ls[r + 16 * i][c4 + 2] = v.z;
        Ls[r + 16 * i][c4 + 3] = v.w;
    }
    __syncthreads();

    // write transposed, split hi/lo, 4 bf16 packed per 8B store
#pragma unroll
    for (int i = 0; i < 4; i++) {
        const int orow = r + 16 * i;             // local col index = out row
        float a0 = Ls[c4 + 0][orow];
        float a1 = Ls[c4 + 1][orow];
        float a2 = Ls[c4 + 2][orow];
        float a3 = Ls[c4 + 3][orow];
        unsigned short h0 = bf16rn(a0), h1 = bf16rn(a1), h2 = bf16rn(a2), h3 = bf16rn(a3);
        float l0f = a0 - bf16tof(h0);
        float l1f = a1 - bf16tof(h1);
        float l2f = a2 - bf16tof(h2);
        float l3f = a3 - bf16tof(h3);
        unsigned short l0 = bf16rn(l0f), l1 = bf16rn(l1f), l2 = bf16rn(l2f), l3 = bf16rn(l3f);
        unsigned long long hp = (unsigned long long)h0 | ((unsigned long long)h1 << 16)
                              | ((unsigned long long)h2 << 32) | ((unsigned long long)h3 << 48);
        unsigned long long lp = (unsigned long long)l0 | ((unsigned long long)l1 << 16)
                              | ((unsigned long long)l2 << 32) | ((unsigned long long)l3 << 48);
        const size_t o = (size_t)(c0 + orow) * FF + f0 + c4;
        *(unsigned long long*)&dh[o] = hp;
        *(unsigned long long*)&dl[o] = lp;
    }
}

// ---------------------------------------------------------------------------
// Main MFMA GEMM. Block tile 128(u) x 128(t), BK=32, 256 threads = 4 waves
// (2x2 of 64x64). LDS: Ah/Al/Bh/Bl, each [128][32] bf16 (8 KB) = 32 KB.
// Staged via global_load_lds dwordx4: wave wv stages tile wv (8 instrs).
// ---------------------------------------------------------------------------
#define GLL(g, l) __builtin_amdgcn_global_load_lds(                     \
    (const __attribute__((address_space(1))) void*)(g),                 \
    (__attribute__((address_space(3))) void*)(l), 16, 0, 0)

__global__ __launch_bounds__(256)
void snn_mfma_kernel(const unsigned short* __restrict__ wth,
                     const unsigned short* __restrict__ wtl,
                     const unsigned short* __restrict__ xth,
                     const unsigned short* __restrict__ xtl,
                     const float* __restrict__ in, const float* __restrict__ w,
                     float* __restrict__ out) {
    __shared__ unsigned short smem[4 * 128 * 32];  // Ah | Al | Bh | Bl

    const int b  = blockIdx.z;
    const int u0 = blockIdx.y * 128;
    const int t0 = blockIdx.x * 128;

    const int tid = threadIdx.x;
    const int wv  = tid >> 6;        // wave 0..3
    const int ln  = tid & 63;
    const int lr  = ln & 15;         // fragment m/n index
    const int lq  = ln >> 4;         // fragment k-quad
    const int wm  = (wv & 1) * 64;   // wave tile origin (u)
    const int wn  = (wv >> 1) * 64;  // wave tile origin (t)

    // staging source for this wave; all sources have 512-bf16 (1024 B) rows
    const char* gbase;
    if      (wv == 0) gbase = (const char*)wth + (size_t)u0 * (FF * 2);
    else if (wv == 1) gbase = (const char*)wtl + (size_t)u0 * (FF * 2);
    else if (wv == 2) gbase = (const char*)xth + ((size_t)b * TT + t0) * (FF * 2);
    else              gbase = (const char*)xtl + ((size_t)b * TT + t0) * (FF * 2);
    const int lrow = ln >> 2;          // 0..15: row within 16-row stage slab
    const int lseg = (ln & 3) * 16;    // 16B segment within 64B row

    unsigned short* lbase = &smem[wv * 4096];  // this wave's 8 KB tile

    v4f acc[4][4];
#pragma unroll
    for (int i = 0; i < 4; i++)
#pragma unroll
        for (int j = 0; j < 4; j++) {
            v4f zz = {0.0f, 0.0f, 0.0f, 0.0f};
            acc[i][j] = zz;
        }

    for (int f0 = 0; f0 < FF; f0 += 32) {
        // stage this chunk's 4 tiles (8 x global_load_lds dwordx4 per wave)
#pragma unroll
        for (int s = 0; s < 8; s++) {
            const char* ga = gbase + (size_t)(s * 16 + lrow) * (FF * 2) + f0 * 2 + lseg;
            GLL(ga, (char*)lbase + s * 1024);
        }
        __syncthreads();   // compiler drains vmcnt(0) before s_barrier

        // 3 passes: (Ah,Bh), (Ah,Bl), (Al,Bh)
#pragma unroll
        for (int p = 0; p < 3; p++) {
            const unsigned short* Ap = &smem[(p == 2 ? 1 : 0) * 4096];
            const unsigned short* Bp = &smem[(p == 1 ? 3 : 2) * 4096];
            v8s af[4], bfr[4];
#pragma unroll
            for (int i = 0; i < 4; i++)
                af[i] = *(const v8s*)&Ap[(wm + i * 16 + lr) * 32 + lq * 8];
#pragma unroll
            for (int j = 0; j < 4; j++)
                bfr[j] = *(const v8s*)&Bp[(wn + j * 16 + lr) * 32 + lq * 8];
#pragma unroll
            for (int i = 0; i < 4; i++)
#pragma unroll
                for (int j = 0; j < 4; j++)
                    acc[i][j] = __builtin_amdgcn_mfma_f32_16x16x32_bf16(
                        af[i], bfr[j], acc[i][j], 0, 0, 0);
        }
        __syncthreads();   // before next chunk overwrites LDS
    }

    // Epilogue. C/D layout (m89-verified): col = lane&15, row = (lane>>4)*4+reg.
    const float* xb   = in  + (size_t)b * FF * TT;
    float* __restrict__ outb = out + (size_t)b * UU * TT;
#pragma unroll
    for (int i = 0; i < 4; i++) {
#pragma unroll
        for (int r = 0; r < 4; r++) {
            const int u = u0 + wm + i * 16 + lq * 4 + r;
#pragma unroll
            for (int j = 0; j < 4; j++) {
                const int t = t0 + wn + j * 16 + lr;
                float h = acc[i][j][r];
                if (__builtin_expect(__builtin_fabsf(h - 1.0f) <= 1e-3f, 0)) {
                    // exact fp32 recompute: identical sequential fmaf order
                    // (f ascending from 0) as the verified fp32 kernel.
                    float s2 = 0.0f;
                    const float* wp = w  + u;
                    const float* xp = xb + t;
#pragma unroll 16
                    for (int f = 0; f < FF; f++)
                        s2 = fmaf(wp[(size_t)f * UU], xp[(size_t)f * TT], s2);
                    h = s2;
                }
                outb[(size_t)u * TT + t] = h > 1.0f ? 1.0f : 0.0f;
            }
        }
    }
}

// ---------------------------------------------------------------------------
// Fallback: previous verified fp32 vector-FMA kernel (used if ws too small).
// ---------------------------------------------------------------------------
__global__ __launch_bounds__(256, 4)
void snn_gemm_kernel(const float* __restrict__ in, const float* __restrict__ w,
                     float* __restrict__ out) {
    __shared__ float As[16][128];
    __shared__ float Bs[16][128];

    const int b  = blockIdx.z;
    const int u0 = blockIdx.y * 128;
    const int t0 = blockIdx.x * 128;

    const float* __restrict__ inb  = in  + (size_t)b * FF * TT;
    float* __restrict__       outb = out + (size_t)b * UU * TT;

    const int tid = threadIdx.x;
    const int tx  = tid & 15;
    const int ty  = tid >> 4;

    const int k0 = tid >> 5;
    const int c0 = (tid & 31) * 4;
    const int k1 = k0 + 8;

    float acc[8][8];
#pragma unroll
    for (int i = 0; i < 8; i++)
#pragma unroll
        for (int j = 0; j < 8; j++) acc[i][j] = 0.0f;

    float4 a_r0 = *(const float4*)&w[(size_t)k0 * UU + u0 + c0];
    float4 a_r1 = *(const float4*)&w[(size_t)k1 * UU + u0 + c0];
    float4 b_r0 = *(const float4*)&inb[k0 * TT + t0 + c0];
    float4 b_r1 = *(const float4*)&inb[k1 * TT + t0 + c0];

    for (int f0 = 0; f0 < FF; f0 += 16) {
        *(float4*)&As[k0][c0] = a_r0;
        *(float4*)&As[k1][c0] = a_r1;
        *(float4*)&Bs[k0][c0] = b_r0;
        *(float4*)&Bs[k1][c0] = b_r1;
        __syncthreads();

        if (f0 + 16 < FF) {
            const int fn = f0 + 16;
            a_r0 = *(const float4*)&w[(size_t)(fn + k0) * UU + u0 + c0];
            a_r1 = *(const float4*)&w[(size_t)(fn + k1) * UU + u0 + c0];
            b_r0 = *(const float4*)&inb[(fn + k0) * TT + t0 + c0];
            b_r1 = *(const float4*)&inb[(fn + k1) * TT + t0 + c0];
        }

#pragma unroll
        for (int k = 0; k < 16; k++) {
            const float4 a0 = *(const float4*)&As[k][ty * 4];
            const float4 a1 = *(const float4*)&As[k][ty * 4 + 64];
            const float4 v0 = *(const float4*)&Bs[k][tx * 4];
            const float4 v1 = *(const float4*)&Bs[k][tx * 4 + 64];
            const float am[8] = {a0.x, a0.y, a0.z, a0.w, a1.x, a1.y, a1.z, a1.w};
            const float bn[8] = {v0.x, v0.y, v0.z, v0.w, v1.x, v1.y, v1.z, v1.w};
#pragma unroll
            for (int i = 0; i < 8; i++)
#pragma unroll
                for (int j = 0; j < 8; j++)
                    acc[i][j] = fmaf(am[i], bn[j], acc[i][j]);
        }
        __syncthreads();
    }

#pragma unroll
    for (int i = 0; i < 8; i++) {
        const int m = (i < 4) ? (ty * 4 + i) : (64 + ty * 4 + i - 4);
        float* __restrict__ orow = outb + (size_t)(u0 + m) * TT + t0;
        float4 o0, o1;
        o0.x = acc[i][0] > 1.0f ? 1.0f : 0.0f;
        o0.y = acc[i][1] > 1.0f ? 1.0f : 0.0f;
        o0.z = acc[i][2] > 1.0f ? 1.0f : 0.0f;
        o0.w = acc[i][3] > 1.0f ? 1.0f : 0.0f;
        o1.x = acc[i][4] > 1.0f ? 1.0f : 0.0f;
        o1.y = acc[i][5] > 1.0f ? 1.0f : 0.0f;
        o1.z = acc[i][6] > 1.0f ? 1.0f : 0.0f;
        o1.w = acc[i][7] > 1.0f ? 1.0f : 0.0f;
        *(float4*)&orow[tx * 4]      = o0;
        *(float4*)&orow[tx * 4 + 64] = o1;
    }
}

extern "C" void kernel_launch(void* const* d_in, const int* in_sizes, int n_in,
                              void* d_out, int out_size, void* d_ws, size_t ws_size,
                              hipStream_t stream) {
    const float* in = (const float*)d_in[0];  // [128,512,256]
    const float* w  = (const float*)d_in[1];  // [512,1024]
    float* out      = (float*)d_out;          // [128,1024,256]

    const size_t XN  = (size_t)BB * TT * FF;   // elements per xT array
    const size_t WN  = (size_t)UU * FF;        // elements per wT array
    const size_t NEED = (2 * XN + 2 * WN) * sizeof(unsigned short);  // 69,206,016 B

    if (ws_size >= NEED) {
        unsigned short* xth = (unsigned short*)d_ws;
        unsigned short* xtl = xth + XN;
        unsigned short* wth = xtl + XN;
        unsigned short* wtl = wth + WN;
        // prepass: 4 col-tiles x 8 f-tiles x (128 X panels + 4 W strips)
        prepass_kernel<<<dim3(4, 8, 132), dim3(256), 0, stream>>>(in, w, xth, xtl, wth, wtl);
        snn_mfma_kernel<<<dim3(TT / 128, UU / 128, BB), dim3(256), 0, stream>>>(
            wth, wtl, xth, xtl, in, w, out);
    } else {
        snn_gemm_kernel<<<dim3(TT / 128, UU / 128, BB), dim3(256), 0, stream>>>(in, w, out);
    }
}

// Round 2
// 481.640 us; speedup vs baseline: 1.2788x; 1.2788x over previous
//
#include <hip/hip_runtime.h>

// snn_layer: out[b,u,t] = (sum_f in[b,f,t] * w[f,u] > 1.0f) ? 1.0f : 0.0f
// B=128 F=512 T=256 U=1024, fp32 in/out.
//
// fp32 has no MFMA on CDNA4 -> exact bf16 hi/lo split, 3-pass MFMA:
//   h ~= Ah*Bh + Ah*Bl + Al*Bh   (error ~1e-5; threshold band |h-1|<=1e-3
// recomputed in fp32 with the verified sequential-fmaf order -> flip-free).
//
// Round-2 changes (counter-driven):
//  * FETCH was 507 MB (7x ideal): XCD-chunked b-major block swizzle so each
//    XCD keeps the whole 2 MB W hot in its L2 and reuses each 512 KB X
//    panel across its 16 consecutive blocks.
//  * SQ_LDS_BANK_CONFLICT was 8.4M (8-way on fragment ds_read_b128):
//    both-sides XOR swizzle -- global_load_lds dest stays LINEAR, the
//    global SOURCE segment is permuted seg^=(row>>1)&3 and the read applies
//    the same involution (guide rule #21). 2-way residual = free.
//  * LDS pipe was over-subscribed (24 b128 reads/wave/chunk): load each
//    fragment once (ah/al/bh/bl = 16 reads), then all 48 MFMAs.

#define BB 128
#define FF 512
#define TT 256
#define UU 1024

typedef float v4f __attribute__((ext_vector_type(4)));
typedef short v8s __attribute__((ext_vector_type(8)));

__device__ __forceinline__ unsigned short bf16rn(float x) {
    unsigned u = __float_as_uint(x);
    u = u + 0x7FFFu + ((u >> 16) & 1u);   // round-to-nearest-even
    return (unsigned short)(u >> 16);
}
__device__ __forceinline__ float bf16tof(unsigned short h) {
    return __uint_as_float(((unsigned)h) << 16);
}

// ---------------------------------------------------------------------------
// Prepass: transpose + hi/lo split (unchanged from verified round-1 version).
// ---------------------------------------------------------------------------
__global__ __launch_bounds__(256)
void prepass_kernel(const float* __restrict__ in, const float* __restrict__ w,
                    unsigned short* __restrict__ xth, unsigned short* __restrict__ xtl,
                    unsigned short* __restrict__ wth, unsigned short* __restrict__ wtl) {
    __shared__ float Ls[64][65];

    const int z = blockIdx.z;
    const float* src;
    int srow;
    unsigned short *dh, *dl;
    if (z < BB) {
        src = in + (size_t)z * FF * TT;  srow = TT;
        dh = xth + (size_t)z * TT * FF;  dl = xtl + (size_t)z * TT * FF;
    } else {
        const int s = z - BB;
        src = w + s * 256;               srow = UU;
        dh = wth + (size_t)s * 256 * FF; dl = wtl + (size_t)s * 256 * FF;
    }
    const int f0 = blockIdx.y * 64;
    const int c0 = blockIdx.x * 64;
    const int tid = threadIdx.x;
    const int r  = tid >> 4;
    const int c4 = (tid & 15) * 4;

#pragma unroll
    for (int i = 0; i < 4; i++) {
        const float4 v = *(const float4*)&src[(size_t)(f0 + r + 16 * i) * srow + c0 + c4];
        Ls[r + 16 * i][c4 + 0] = v.x;
        Ls[r + 16 * i][c4 + 1] = v.y;
        Ls[r + 16 * i][c4 + 2] = v.z;
        Ls[r + 16 * i][c4 + 3] = v.w;
    }
    __syncthreads();

#pragma unroll
    for (int i = 0; i < 4; i++) {
        const int orow = r + 16 * i;
        float a0 = Ls[c4 + 0][orow];
        float a1 = Ls[c4 + 1][orow];
        float a2 = Ls[c4 + 2][orow];
        float a3 = Ls[c4 + 3][orow];
        unsigned short h0 = bf16rn(a0), h1 = bf16rn(a1), h2 = bf16rn(a2), h3 = bf16rn(a3);
        float l0f = a0 - bf16tof(h0);
        float l1f = a1 - bf16tof(h1);
        float l2f = a2 - bf16tof(h2);
        float l3f = a3 - bf16tof(h3);
        unsigned short l0 = bf16rn(l0f), l1 = bf16rn(l1f), l2 = bf16rn(l2f), l3 = bf16rn(l3f);
        unsigned long long hp = (unsigned long long)h0 | ((unsigned long long)h1 << 16)
                              | ((unsigned long long)h2 << 32) | ((unsigned long long)h3 << 48);
        unsigned long long lp = (unsigned long long)l0 | ((unsigned long long)l1 << 16)
                              | ((unsigned long long)l2 << 32) | ((unsigned long long)l3 << 48);
        const size_t o = (size_t)(c0 + orow) * FF + f0 + c4;
        *(unsigned long long*)&dh[o] = hp;
        *(unsigned long long*)&dl[o] = lp;
    }
}

// ---------------------------------------------------------------------------
// Main MFMA GEMM. 128x128 tile, BK=32, 4 waves (2x2 of 64x64).
// LDS: Ah|Al|Bh|Bl, each [128 rows][32 bf16] (linear dest for
// global_load_lds); k-segments pre-permuted at the global source.
// ---------------------------------------------------------------------------
#define GLL(g, l) __builtin_amdgcn_global_load_lds(                     \
    (const __attribute__((address_space(1))) void*)(g),                 \
    (__attribute__((address_space(3))) void*)(l), 16, 0, 0)

__global__ __launch_bounds__(256, 3)
void snn_mfma_kernel(const unsigned short* __restrict__ wth,
                     const unsigned short* __restrict__ wtl,
                     const unsigned short* __restrict__ xth,
                     const unsigned short* __restrict__ xtl,
                     const float* __restrict__ in, const float* __restrict__ w,
                     float* __restrict__ out) {
    __shared__ unsigned short smem[4 * 128 * 32];  // Ah | Al | Bh | Bl

    // XCD-chunked, b-major swizzle: hw id h -> logical l; each XCD gets 256
    // consecutive l = 16 consecutive b (W fully L2-hot, X panel 16-block hot).
    const int h = blockIdx.x;
    const int l = ((h & 7) << 8) | (h >> 3);
    const int b  = l >> 4;
    const int u0 = ((l >> 1) & 7) * 128;
    const int t0 = (l & 1) * 128;

    const int tid = threadIdx.x;
    const int wv  = tid >> 6;        // wave 0..3
    const int ln  = tid & 63;
    const int lr  = ln & 15;         // fragment m/n index
    const int lq  = ln >> 4;         // fragment k-quad
    const int wm  = (wv & 1) * 64;   // wave tile origin (u)
    const int wn  = (wv >> 1) * 64;  // wave tile origin (t)

    // staging source for this wave; all sources have 1024-B rows
    const char* gbase;
    if      (wv == 0) gbase = (const char*)wth + (size_t)u0 * (FF * 2);
    else if (wv == 1) gbase = (const char*)wtl + (size_t)u0 * (FF * 2);
    else if (wv == 2) gbase = (const char*)xth + ((size_t)b * TT + t0) * (FF * 2);
    else              gbase = (const char*)xtl + ((size_t)b * TT + t0) * (FF * 2);
    const int lrow = ln >> 2;                               // row within 16-row slab
    const int lseg = (((ln & 3) ^ ((lrow >> 1) & 3)) * 16); // XOR-swizzled source seg

    unsigned short* lbase = &smem[wv * 4096];

    v4f acc[4][4];
#pragma unroll
    for (int i = 0; i < 4; i++)
#pragma unroll
        for (int j = 0; j < 4; j++) {
            v4f zz = {0.0f, 0.0f, 0.0f, 0.0f};
            acc[i][j] = zz;
        }

    // read-side segment select: same involution as the staged source
    const int ksel = (lq ^ ((lr >> 1) & 3)) * 8;

    for (int f0 = 0; f0 < FF; f0 += 32) {
#pragma unroll
        for (int s = 0; s < 8; s++) {
            const char* ga = gbase + (size_t)(s * 16 + lrow) * (FF * 2) + f0 * 2 + lseg;
            GLL(ga, (char*)lbase + s * 1024);
        }
        __syncthreads();   // drains vmcnt(0) before s_barrier

        // load each fragment ONCE (16 ds_read_b128), then all 48 MFMAs
        v8s ah[4], al[4], bh[4], bl[4];
#pragma unroll
        for (int i = 0; i < 4; i++) {
            const int ra = (wm + i * 16 + lr) * 32 + ksel;
            ah[i] = *(const v8s*)&smem[ra];
            al[i] = *(const v8s*)&smem[4096 + ra];
        }
#pragma unroll
        for (int j = 0; j < 4; j++) {
            const int rb = (wn + j * 16 + lr) * 32 + ksel;
            bh[j] = *(const v8s*)&smem[8192 + rb];
            bl[j] = *(const v8s*)&smem[12288 + rb];
        }
#pragma unroll
        for (int i = 0; i < 4; i++)
#pragma unroll
            for (int j = 0; j < 4; j++) {
                acc[i][j] = __builtin_amdgcn_mfma_f32_16x16x32_bf16(ah[i], bh[j], acc[i][j], 0, 0, 0);
                acc[i][j] = __builtin_amdgcn_mfma_f32_16x16x32_bf16(ah[i], bl[j], acc[i][j], 0, 0, 0);
                acc[i][j] = __builtin_amdgcn_mfma_f32_16x16x32_bf16(al[i], bh[j], acc[i][j], 0, 0, 0);
            }
        __syncthreads();   // before next chunk overwrites LDS
    }

    // Epilogue. C/D layout: col = lane&15, row = (lane>>4)*4+reg.
    const float* xb   = in  + (size_t)b * FF * TT;
    float* __restrict__ outb = out + (size_t)b * UU * TT;
#pragma unroll
    for (int i = 0; i < 4; i++) {
#pragma unroll
        for (int r = 0; r < 4; r++) {
            const int u = u0 + wm + i * 16 + lq * 4 + r;
#pragma unroll
            for (int j = 0; j < 4; j++) {
                const int t = t0 + wn + j * 16 + lr;
                float hh = acc[i][j][r];
                if (__builtin_expect(__builtin_fabsf(hh - 1.0f) <= 1e-3f, 0)) {
                    // exact fp32 recompute: identical sequential fmaf order
                    // (f ascending from 0) as the verified fp32 kernel.
                    float s2 = 0.0f;
                    const float* wp = w  + u;
                    const float* xp = xb + t;
#pragma unroll 16
                    for (int f = 0; f < FF; f++)
                        s2 = fmaf(wp[(size_t)f * UU], xp[(size_t)f * TT], s2);
                    hh = s2;
                }
                outb[(size_t)u * TT + t] = hh > 1.0f ? 1.0f : 0.0f;
            }
        }
    }
}

// ---------------------------------------------------------------------------
// Fallback: previous verified fp32 vector-FMA kernel (used if ws too small).
// ---------------------------------------------------------------------------
__global__ __launch_bounds__(256, 4)
void snn_gemm_kernel(const float* __restrict__ in, const float* __restrict__ w,
                     float* __restrict__ out) {
    __shared__ float As[16][128];
    __shared__ float Bs[16][128];

    const int b  = blockIdx.z;
    const int u0 = blockIdx.y * 128;
    const int t0 = blockIdx.x * 128;

    const float* __restrict__ inb  = in  + (size_t)b * FF * TT;
    float* __restrict__       outb = out + (size_t)b * UU * TT;

    const int tid = threadIdx.x;
    const int tx  = tid & 15;
    const int ty  = tid >> 4;

    const int k0 = tid >> 5;
    const int c0 = (tid & 31) * 4;
    const int k1 = k0 + 8;

    float acc[8][8];
#pragma unroll
    for (int i = 0; i < 8; i++)
#pragma unroll
        for (int j = 0; j < 8; j++) acc[i][j] = 0.0f;

    float4 a_r0 = *(const float4*)&w[(size_t)k0 * UU + u0 + c0];
    float4 a_r1 = *(const float4*)&w[(size_t)k1 * UU + u0 + c0];
    float4 b_r0 = *(const float4*)&inb[k0 * TT + t0 + c0];
    float4 b_r1 = *(const float4*)&inb[k1 * TT + t0 + c0];

    for (int f0 = 0; f0 < FF; f0 += 16) {
        *(float4*)&As[k0][c0] = a_r0;
        *(float4*)&As[k1][c0] = a_r1;
        *(float4*)&Bs[k0][c0] = b_r0;
        *(float4*)&Bs[k1][c0] = b_r1;
        __syncthreads();

        if (f0 + 16 < FF) {
            const int fn = f0 + 16;
            a_r0 = *(const float4*)&w[(size_t)(fn + k0) * UU + u0 + c0];
            a_r1 = *(const float4*)&w[(size_t)(fn + k1) * UU + u0 + c0];
            b_r0 = *(const float4*)&inb[(fn + k0) * TT + t0 + c0];
            b_r1 = *(const float4*)&inb[(fn + k1) * TT + t0 + c0];
        }

#pragma unroll
        for (int k = 0; k < 16; k++) {
            const float4 a0 = *(const float4*)&As[k][ty * 4];
            const float4 a1 = *(const float4*)&As[k][ty * 4 + 64];
            const float4 v0 = *(const float4*)&Bs[k][tx * 4];
            const float4 v1 = *(const float4*)&Bs[k][tx * 4 + 64];
            const float am[8] = {a0.x, a0.y, a0.z, a0.w, a1.x, a1.y, a1.z, a1.w};
            const float bn[8] = {v0.x, v0.y, v0.z, v0.w, v1.x, v1.y, v1.z, v1.w};
#pragma unroll
            for (int i = 0; i < 8; i++)
#pragma unroll
                for (int j = 0; j < 8; j++)
                    acc[i][j] = fmaf(am[i], bn[j], acc[i][j]);
        }
        __syncthreads();
    }

#pragma unroll
    for (int i = 0; i < 8; i++) {
        const int m = (i < 4) ? (ty * 4 + i) : (64 + ty * 4 + i - 4);
        float* __restrict__ orow = outb + (size_t)(u0 + m) * TT + t0;
        float4 o0, o1;
        o0.x = acc[i][0] > 1.0f ? 1.0f : 0.0f;
        o0.y = acc[i][1] > 1.0f ? 1.0f : 0.0f;
        o0.z = acc[i][2] > 1.0f ? 1.0f : 0.0f;
        o0.w = acc[i][3] > 1.0f ? 1.0f : 0.0f;
        o1.x = acc[i][4] > 1.0f ? 1.0f : 0.0f;
        o1.y = acc[i][5] > 1.0f ? 1.0f : 0.0f;
        o1.z = acc[i][6] > 1.0f ? 1.0f : 0.0f;
        o1.w = acc[i][7] > 1.0f ? 1.0f : 0.0f;
        *(float4*)&orow[tx * 4]      = o0;
        *(float4*)&orow[tx * 4 + 64] = o1;
    }
}

extern "C" void kernel_launch(void* const* d_in, const int* in_sizes, int n_in,
                              void* d_out, int out_size, void* d_ws, size_t ws_size,
                              hipStream_t stream) {
    const float* in = (const float*)d_in[0];  // [128,512,256]
    const float* w  = (const float*)d_in[1];  // [512,1024]
    float* out      = (float*)d_out;          // [128,1024,256]

    const size_t XN  = (size_t)BB * TT * FF;
    const size_t WN  = (size_t)UU * FF;
    const size_t NEED = (2 * XN + 2 * WN) * sizeof(unsigned short);

    if (ws_size >= NEED) {
        unsigned short* xth = (unsigned short*)d_ws;
        unsigned short* xtl = xth + XN;
        unsigned short* wth = xtl + XN;
        unsigned short* wtl = wth + WN;
        prepass_kernel<<<dim3(4, 8, 132), dim3(256), 0, stream>>>(in, w, xth, xtl, wth, wtl);
        snn_mfma_kernel<<<dim3(2048), dim3(256), 0, stream>>>(
            wth, wtl, xth, xtl, in, w, out);
    } else {
        snn_gemm_kernel<<<dim3(TT / 128, UU / 128, BB), dim3(256), 0, stream>>>(in, w, out);
    }
}